// Round 7
// baseline (126.216 us; speedup 1.0000x reference)
//
#include <hip/hip_runtime.h>

#define N 8000
#define C 96
#define C4 24
#define OCH 19
#define NCELL 1000
#define NCH 32
#define HSZ (NCELL*NCH)
#define U1 (1.0f/8000.0f)
#define RCH 16
#define KCAP 192

__device__ __forceinline__ int clamp10(int v) { return min(max(v, 0), 9); }

// ---------------- fused prep: B-side (+per-block diff), softmax, A-side, copies + ws init ----------------
__global__ void __launch_bounds__(256) k_prep(
    const float* __restrict__ sf, const float* __restrict__ coords,
    const float* __restrict__ posses, const float* __restrict__ sv_prob,
    const float* __restrict__ mf, const float* __restrict__ ori,
    float* __restrict__ w2, float4* __restrict__ alN,
    int* __restrict__ cellB, int* __restrict__ histB,
    float4* __restrict__ oriN, int* __restrict__ cellA, int* __restrict__ histA,
    float* __restrict__ svp,
    float* __restrict__ o_mf, float* __restrict__ o_ori,
    float4* __restrict__ ck4, int4* __restrict__ wn4, int* __restrict__ flags) {
    int bx = blockIdx.x, tid = threadIdx.x;
    if (bx < 32) {
        __shared__ float sdiff[12];
        if (tid == 0) {
            double M[4][8];
            for (int r = 0; r < 4; ++r)
                for (int c = 0; c < 4; ++c) {
                    M[r][c] = (double)posses[16 + r*4 + c];
                    M[r][4+c] = (r == c) ? 1.0 : 0.0;
                }
            for (int col = 0; col < 4; ++col) {
                int piv = col; double best = fabs(M[col][col]);
                for (int r = col+1; r < 4; ++r) { double v = fabs(M[r][col]); if (v > best) { best = v; piv = r; } }
                if (piv != col) for (int c = 0; c < 8; ++c) { double t = M[col][c]; M[col][c] = M[piv][c]; M[piv][c] = t; }
                double inv = 1.0 / M[col][col];
                for (int c = 0; c < 8; ++c) M[col][c] *= inv;
                for (int r = 0; r < 4; ++r) if (r != col) {
                    double f = M[r][col];
                    for (int c = 0; c < 8; ++c) M[r][c] -= f * M[col][c];
                }
            }
            for (int r = 0; r < 3; ++r)
                for (int c = 0; c < 4; ++c) {
                    double s = 0.0;
                    for (int k = 0; k < 4; ++k) s += M[r][4+k] * (double)posses[k*4 + c];
                    sdiff[r*4 + c] = (float)s;
                }
        }
        __syncthreads();
        int j = bx*256 + tid;
        if (j < N) {
            const float4* s4 = (const float4*)sf + j*C4;
            float s = 0.f;
            for (int kk = 0; kk < C4; ++kk) {
                float4 v = s4[kk];
                s += v.x*v.x; s += v.y*v.y; s += v.z*v.z; s += v.w*v.w;
            }
            w2[j] = sqrtf(s);
            float c0 = coords[j*3], c1 = coords[j*3+1], c2 = coords[j*3+2];
            float a0 = (sdiff[0]*c0 + sdiff[1]*c1) + (sdiff[2]*c2 + sdiff[3]);
            float a1 = (sdiff[4]*c0 + sdiff[5]*c1) + (sdiff[6]*c2 + sdiff[7]);
            float a2 = (sdiff[8]*c0 + sdiff[9]*c1) + (sdiff[10]*c2 + sdiff[11]);
            alN[j] = make_float4(a0, a1, a2, a0*a0 + a1*a1 + a2*a2);
            int cx = clamp10((int)floorf((a0 + 25.f) * 0.2f));
            int cy = clamp10((int)floorf((a1 + 25.f) * 0.2f));
            int cz = clamp10((int)floorf((a2 + 25.f) * 0.2f));
            int cc = (cz*10 + cy)*10 + cx;
            cellB[j] = cc;
            atomicAdd(&histB[cc*NCH + bx], 1);
        }
    } else if (bx < 64) {
        int i = (bx-32)*256 + tid;
        if (i >= N) return;
        float m = -1e30f;
        for (int c = 0; c < OCH; ++c) m = fmaxf(m, sv_prob[i*OCH + c]);
        float e[OCH]; float s = 0.f;
        for (int c = 0; c < OCH; ++c) { e[c] = expf(sv_prob[i*OCH + c] - m); s += e[c]; }
        for (int c = 0; c < OCH; ++c) svp[i*OCH + c] = e[c] / s;
    } else if (bx < 96) {
        // A-side: cell of ori coords, histogram, packed coords+norm
        int i = (bx-64)*256 + tid;
        if (i >= N) return;
        float ox = ori[i*3], oy = ori[i*3+1], oz = ori[i*3+2];
        oriN[i] = make_float4(ox, oy, oz, ox*ox + oy*oy + oz*oz);
        int cx = clamp10((int)floorf((ox + 25.f) * 0.2f));
        int cy = clamp10((int)floorf((oy + 25.f) * 0.2f));
        int cz = clamp10((int)floorf((oz + 25.f) * 0.2f));
        int cc = (cz*10 + cy)*10 + cx;
        cellA[i] = cc;
        atomicAdd(&histA[cc*NCH + (bx-64)], 1);
    } else {
        // copies + workspace init (colkey zero, winnerHi|winnerLo 0xFF, flags zero)
        const float4* mf4 = (const float4*)mf;
        const float4* ori4 = (const float4*)ori;
        float4* omf4 = (float4*)o_mf;
        float4* oori4 = (float4*)o_ori;
        float4 z4 = make_float4(0.f, 0.f, 0.f, 0.f);
        int4 f4 = make_int4(-1, -1, -1, -1);
        int t0 = (bx-96)*256 + tid;
        for (int t = t0; t < 206000; t += 160*256) {
            if (t < 192000) omf4[t] = mf4[t];
            else if (t < 198000) oori4[t-192000] = ori4[t-192000];
            else if (t < 202000) ck4[t-198000] = z4;
            else wn4[t-202000] = f4;
        }
        if (bx == 96 && tid < 8) flags[tid] = 0;
    }
}

// ---------------- exclusive scan over [cell][chunk] histograms + cell starts (block 0: A, 1: B) ----------------
__global__ void __launch_bounds__(1024) k_scan(int* __restrict__ hA, int* __restrict__ csA_,
                                               int* __restrict__ hB, int* __restrict__ csB_) {
    int* h  = blockIdx.x ? hB : hA;
    int* cs = blockIdx.x ? csB_ : csA_;
    int tid = threadIdx.x;
    int base = tid * 32;
    int v[32]; int s = 0;
    #pragma unroll
    for (int t = 0; t < 32; ++t) { int idx = base + t; int x = (idx < HSZ) ? h[idx] : 0; v[t] = x; s += x; }
    int lane = tid & 63, wv = tid >> 6;
    int x = s;
    for (int off = 1; off < 64; off <<= 1) { int y = __shfl_up(x, off); if (lane >= off) x += y; }
    __shared__ int wtot[16];
    if (lane == 63) wtot[wv] = x;
    __syncthreads();
    int wpre = 0;
    for (int t = 0; t < 16; ++t) if (t < wv) wpre += wtot[t];
    int run = wpre + x - s;
    #pragma unroll
    for (int t = 0; t < 32; ++t) { int idx = base + t; if (idx < HSZ) h[idx] = run; run += v[t]; }
    __syncthreads();
    for (int c = tid; c < NCELL; c += 1024) cs[c] = h[c*NCH];
    if (tid == 0) cs[NCELL] = N;
}

// ---------------- deterministic stable scatter: blocks 0-31 B-side (+fT4 build), 32-63 A-side ----------------
__global__ void k_scatter(const int* __restrict__ cellB, const int* __restrict__ startB,
                          const float* __restrict__ w2, const float4* __restrict__ alN,
                          const float4* __restrict__ sf4,
                          int* __restrict__ idBR, float* __restrict__ w2R,
                          float4* __restrict__ alR, float4* __restrict__ fT4,
                          const int* __restrict__ cellA, const int* __restrict__ startA,
                          const float4* __restrict__ oriN,
                          int* __restrict__ idAR, float4* __restrict__ oriAR) {
    __shared__ int sc[256];
    int bx = blockIdx.x, tid = threadIdx.x;
    bool isB = bx < 32;
    int chunk = isB ? bx : bx - 32;
    int gi = chunk*256 + tid;
    const int* cellArr = isB ? cellB : cellA;
    int cell = (gi < N) ? cellArr[gi] : -1;
    sc[tid] = cell;
    __syncthreads();
    if (gi >= N) return;
    int rank = 0;
    for (int t = 0; t < tid; ++t) rank += (sc[t] == cell);
    if (isB) {
        int pos = startB[cell*NCH + chunk] + rank;
        idBR[pos] = gi;
        w2R[pos] = w2[gi];
        alR[pos] = alN[gi];
        const float4* src = sf4 + gi*C4;
        #pragma unroll
        for (int kk = 0; kk < C4; ++kk) fT4[kk*N + pos] = src[kk];
    } else {
        int pos = startA[cell*NCH + chunk] + rank;
        idAR[pos] = gi;
        oriAR[pos] = oriN[gi];
    }
}

// ---------------- cell-blocked pass: shared candidate tiles, 16 rows reuse each tile ----------------
__global__ void __launch_bounds__(256) k_cells(
    const float4* __restrict__ mf4, const float4* __restrict__ fT4,
    const int* __restrict__ idAR, const float4* __restrict__ oriAR,
    const int* __restrict__ csA,
    const float4* __restrict__ alR, const float* __restrict__ w2R,
    const int* __restrict__ idBR, const int* __restrict__ csB,
    unsigned long long* __restrict__ colkey) {
    __shared__ float4 sRowA[RCH][C4];
    __shared__ float4 sFeat[C4][64];
    __shared__ float4 sOri[RCH];
    __shared__ float sW1[RCH];
    __shared__ int sIdA[RCH];
    __shared__ unsigned short sJ2[RCH][KCAP];
    __shared__ float sK2[RCH][KCAP];

    int cell = blockIdx.x;
    int rA0 = csA[cell] + blockIdx.y * RCH;
    int rA1 = min(csA[cell+1], rA0 + RCH);
    if (rA0 >= rA1) return;
    int nR = rA1 - rA0;

    int tid = threadIdx.x, lane = tid & 63, w = tid >> 6;

    if (tid < nR) {
        sIdA[tid] = idAR[rA0 + tid];
        sOri[tid] = oriAR[rA0 + tid];
    }
    __syncthreads();
    for (int idx = tid; idx < nR*C4; idx += 256) {
        int r = idx / C4, kk = idx - r*C4;
        sRowA[r][kk] = mf4[sIdA[r]*C4 + kk];
    }
    __syncthreads();
    if (tid < nR) {
        // w1 in the exact sequential order of previous validated rounds
        float s = 0.f;
        for (int kk = 0; kk < C4; ++kk) {
            float4 v = sRowA[tid][kk];
            s += v.x*v.x; s += v.y*v.y; s += v.z*v.z; s += v.w*v.w;
        }
        sW1[tid] = sqrtf(s);
    }

    int cx = cell % 10, cy = (cell/10) % 10, cz = cell/100;
    int xlo = max(cx-1, 0), xhi = min(cx+1, 9);
    int s_[9], l_[9], c_[9]; int tot = 0;
    #pragma unroll
    for (int t = 0; t < 9; ++t) {
        int z = cz + t/3 - 1, y = cy + t%3 - 1;
        bool ok = ((unsigned)z <= 9u) && ((unsigned)y <= 9u);
        int ss = 0, ee = 0;
        if (ok) { int cb = (z*10 + y)*10; ss = csB[cb + xlo]; ee = csB[cb + xhi + 1]; }
        s_[t] = ss; l_[t] = ee - ss; c_[t] = tot; tot += ee - ss;
    }
    __syncthreads();   // sW1 / sRowA ready for all waves

    float racc[4] = {0.f, 0.f, 0.f, 0.f};
    int cnt[4] = {0, 0, 0, 0};
    unsigned long long lmask = lane ? (~0ull >> (64 - lane)) : 0ull;

    for (int f0 = 0; f0 < tot; f0 += 64) {
        int f = f0 + lane;
        bool act = f < tot;
        int q = 0;
        #pragma unroll
        for (int t = 0; t < 9; ++t) {
            bool in = (f >= c_[t]) && (f - c_[t] < l_[t]);
            if (in) q = s_[t] + (f - c_[t]);
        }
        float4 aj = alR[q];          // q=0 for inactive lanes: valid memory, masked later
        float w2v = w2R[q];
        int jid = idBR[q];
        __syncthreads();             // previous tile's reads complete before overwrite
        #pragma unroll
        for (int kk6 = 0; kk6 < 6; ++kk6) {
            int kk = w*6 + kk6;
            sFeat[kk][lane] = fT4[kk*N + q];   // coalesced global, conflict-free LDS
        }
        __syncthreads();
        #pragma unroll
        for (int k2 = 0; k2 < 4; ++k2) {
            int r = w + 4*k2;                  // wave-uniform
            if (r >= nR) break;
            float4 o = sOri[r];
            float w1v = sW1[r];
            float d = o.w + aj.w - 2.f*(o.x*aj.x + o.y*aj.y + o.z*aj.z);
            float cdv = fmaxf(d, 0.f) * 4.f;
            bool mask = act && (cdv < 100.f);
            float ax = 0.f, ay = 0.f, az = 0.f, aw = 0.f;
            #pragma unroll
            for (int kk = 0; kk < C4; ++kk) {
                float4 a = sRowA[r][kk];       // broadcast read
                float4 b = sFeat[kk][lane];    // lane-major, conflict-free
                ax += a.x*b.x; ay += a.y*b.y; az += a.z*b.z; aw += a.w*b.w;
            }
            float dot = (ax + ay) + (az + aw);
            float fdc = 1.f - dot / fmaxf(w1v * w2v, 1e-8f);
            float dist = (1.f + fdc) - expf(-0.5f * cdv);
            float K = expf(-dist / 0.03f);
            unsigned long long m = __ballot(mask);
            if (mask) {
                int idx = cnt[k2] + __popcll(m & lmask);
                if (idx < KCAP) { sJ2[r][idx] = (unsigned short)jid; sK2[r][idx] = K; }
            }
            cnt[k2] += __popcll(m);
            racc[k2] += mask ? K * U1 : 0.f;
        }
    }
    __syncthreads();   // sJ2/sK2 cross-lane visibility

    #pragma unroll
    for (int k2 = 0; k2 < 4; ++k2) {
        int r = w + 4*k2;
        if (r >= nR) break;
        float rs = racc[k2];
        for (int off = 32; off; off >>= 1) rs += __shfl_xor(rs, off);
        float bi = U1 / (rs + 1e-16f);
        int np = min(cnt[k2], KCAP);
        unsigned long long ikey = (unsigned long long)(unsigned)(N - sIdA[r]);
        for (int t = lane; t < np; t += 64) {
            float v = sK2[r][t] * bi;
            if (v > 0.f) {
                unsigned long long key = ((unsigned long long)__float_as_uint(v) << 32) | ikey;
                atomicMax(&colkey[(int)sJ2[r][t]], key);
            }
        }
    }
}

// ---------------- decode colmax -> winner atomics; wave-aggregated flag atomics ----------------
__global__ void k_post(const unsigned long long* __restrict__ colkey,
                       const float* __restrict__ svp, const int* __restrict__ gt,
                       int* __restrict__ winnerHi, int* __restrict__ winnerLo,
                       int* __restrict__ flags) {
    int j = blockIdx.x * 256 + threadIdx.x;
    int lane = threadIdx.x & 63;
    bool valid = j < N;
    float vv = 0.f; int bidx = 0;
    if (valid) {
        unsigned long long key = colkey[j];
        bidx = key ? (N - (int)(key & 0xffffffffull)) : 0;
        vv = svp[bidx*OCH + gt[j]];
    }
    bool hi = valid && (vv > 0.1f);
    bool nothi = valid && !(vv > 0.1f);
    bool lo = valid && (vv > 0.0f);
    bool notlo = valid && !(vv > 0.0f);
    if (hi) atomicMax(&winnerHi[bidx], j);
    if (lo) atomicMax(&winnerLo[bidx], j);
    unsigned long long m0 = __ballot(hi);
    unsigned long long m1 = __ballot(nothi);
    unsigned long long m2 = __ballot(notlo);
    if (lane == 0) {
        if (m0) atomicOr(&flags[0], 1);
        if (m1) atomicOr(&flags[1], 1);
        if (m2) atomicOr(&flags[2], 1);
    }
}

// ---------------- merged outputs: blocks 0-7 rowsout, block 8 trust ----------------
__global__ void __launch_bounds__(1024) k_final(
    const int* __restrict__ winnerHi, const int* __restrict__ winnerLo,
    const int* __restrict__ flags, const int* __restrict__ gt,
    const float* __restrict__ svp,
    float* __restrict__ o_svp, float* __restrict__ o_pre,
    float* __restrict__ out0, float* __restrict__ out5) {
    int bx = blockIdx.x, tid = threadIdx.x;
    const int* winner = flags[0] ? winnerHi : winnerLo;
    if (bx < 8) {
        int i = bx*1024 + tid;
        if (i >= N) return;
        int w = winner[i];
        float row[OCH];
        if (w >= 0) {
            int g = gt[w];
            for (int c = 0; c < OCH; ++c) row[c] = (c == g) ? 1.f : 0.f;
        } else {
            for (int c = 0; c < OCH; ++c) row[c] = svp[i*OCH + c];
        }
        int p = 0; float m = row[0];
        for (int c = 0; c < OCH; ++c) {
            o_svp[i*OCH + c] = row[c];
            if (c > 0 && row[c] > m) { m = row[c]; p = c; }
        }
        o_pre[i] = (float)p;
    } else {
        __shared__ int wsum[16];
        int off = flags[0] ? (flags[1] ? 1 : 0) : (flags[2] ? 1 : 0);
        for (int p = tid; p < N; p += 1024) { out0[p] = -1.f; out5[p] = -1.f; }
        __syncthreads();
        int base = 0;
        for (int round = 0; round < N; round += 1024) {
            int i = round + tid;
            int pres = (i < N && winner[i] >= 0) ? 1 : 0;
            unsigned long long mask = __ballot(pres);
            int lane = tid & 63;
            int wv = tid >> 6;
            int excl = (lane == 0) ? 0 : __popcll(mask & (~0ull >> (64 - lane)));
            if (lane == 0) wsum[wv] = __popcll(mask);
            __syncthreads();
            int wpre = 0, tot = 0;
            for (int t = 0; t < 16; ++t) { if (t < wv) wpre += wsum[t]; tot += wsum[t]; }
            int pos = base + wpre + excl + off;
            if (pres && pos < N) { out0[pos] = (float)i; out5[pos] = (float)i; }
            base += tot;
            __syncthreads();
        }
    }
}

// ---------------- launch ----------------
extern "C" void kernel_launch(void* const* d_in, const int* in_sizes, int n_in,
                              void* d_out, int out_size, void* d_ws, size_t ws_size,
                              hipStream_t stream) {
    const float* sur_feat   = (const float*)d_in[0];
    const float* sur_coords = (const float*)d_in[1];
    const int*   sur_gt     = (const int*)d_in[2];
    const float* sv_prob    = (const float*)d_in[3];
    const float* mean_feat  = (const float*)d_in[4];
    const float* ori        = (const float*)d_in[5];
    const float* posses     = (const float*)d_in[6];

    float* out = (float*)d_out;
    float* o_trust  = out;
    float* o_mf     = out + 8000;
    float* o_ori    = out + 776000;
    float* o_pre    = out + 800000;
    float* o_svp    = out + 808000;
    float* o_trust2 = out + 960000;

    float* w = (float*)d_ws;
    // float4-aligned region first
    float4* alN = (float4*)w;      w += 4*N;      // 32000
    float4* oriN = (float4*)w;     w += 4*N;      // 32000
    float4* alR = (float4*)w;      w += 4*N;      // 32000
    float4* oriAR = (float4*)w;    w += 4*N;      // 32000
    float4* fT4 = (float4*)w;      w += 4*C4*N;   // 768000 (3 MB, CSR-order k-major)
    unsigned long long* colkey = (unsigned long long*)w;  w += 4*N;   // 16000
    // scalar region
    float* w2 = w;                 w += N;
    int* cellB = (int*)w;          w += N;
    int* cellA = (int*)w;          w += N;
    int* histA = (int*)w;          w += HSZ;      // contiguous with histB for one memset
    int* histB = (int*)w;          w += HSZ;
    int* flags = (int*)w;          w += 8;
    int* csA = (int*)w;            w += 1008;
    int* csB = (int*)w;            w += 1008;
    float* svp = w;                w += N*OCH;
    int* idBR = (int*)w;           w += N;
    float* w2R = w;                w += N;
    int* idAR = (int*)w;           w += N;
    int* winnerHi = (int*)w;       w += N;        // contiguous with winnerLo (int4-inited)
    int* winnerLo = (int*)w;       w += N;

    dim3 b256(256);

    hipMemsetAsync(histA, 0, (size_t)(2*HSZ) * 4, stream);

    k_prep<<<256, b256, 0, stream>>>(sur_feat, sur_coords, posses, sv_prob, mean_feat, ori,
                                     w2, alN, cellB, histB, oriN, cellA, histA,
                                     svp, o_mf, o_ori,
                                     (float4*)colkey, (int4*)winnerHi, flags);
    k_scan<<<2, 1024, 0, stream>>>(histA, csA, histB, csB);
    k_scatter<<<64, b256, 0, stream>>>(cellB, histB, w2, alN, (const float4*)sur_feat,
                                       idBR, w2R, alR, fT4,
                                       cellA, histA, oriN, idAR, oriAR);
    k_cells<<<dim3(NCELL, 4), b256, 0, stream>>>((const float4*)mean_feat, fT4, idAR, oriAR, csA,
                                                 alR, w2R, idBR, csB, colkey);
    k_post<<<32, b256, 0, stream>>>(colkey, svp, sur_gt, winnerHi, winnerLo, flags);
    k_final<<<9, 1024, 0, stream>>>(winnerHi, winnerLo, flags, sur_gt, svp,
                                    o_svp, o_pre, o_trust, o_trust2);
}

// Round 8
// 74.997 us; speedup vs baseline: 1.6830x; 1.6830x over previous
//
#include <hip/hip_runtime.h>

#define N 8000
#define C 96
#define C4 24
#define OCH 19
#define NCELL 1000
#define NCH 32
#define HSZ (NCH*NCELL)
#define U1 (1.0f/8000.0f)
#define PAIR_CAP 256

__device__ __forceinline__ int clamp10(int v) { return min(max(v, 0), 9); }

// ---------------- prep: B-side per-point (norm, align, cell, LDS hist) + ws init ----------------
__global__ void __launch_bounds__(256) k_prep(
    const float* __restrict__ sf, const float* __restrict__ coords,
    const float* __restrict__ posses,
    float* __restrict__ w2, float4* __restrict__ alN,
    int* __restrict__ cellB, int* __restrict__ histB,
    int4* __restrict__ ck4, int4* __restrict__ wn4, int* __restrict__ flags) {
    int bx = blockIdx.x, tid = threadIdx.x;
    if (bx < 32) {
        __shared__ int lhist[NCELL];
        __shared__ float sdiff[12];
        for (int c = tid; c < NCELL; c += 256) lhist[c] = 0;
        int j = bx*256 + tid;
        // feature norm first: global loads overlap the tid0 serial inverse
        float s = 0.f;
        if (j < N) {
            const float4* s4 = (const float4*)sf + j*C4;
            for (int kk = 0; kk < C4; ++kk) {
                float4 v = s4[kk];
                s += v.x*v.x; s += v.y*v.y; s += v.z*v.z; s += v.w*v.w;
            }
        }
        if (tid == 0) {
            double M[4][8];
            for (int r = 0; r < 4; ++r)
                for (int c = 0; c < 4; ++c) {
                    M[r][c] = (double)posses[16 + r*4 + c];
                    M[r][4+c] = (r == c) ? 1.0 : 0.0;
                }
            for (int col = 0; col < 4; ++col) {
                int piv = col; double best = fabs(M[col][col]);
                for (int r = col+1; r < 4; ++r) { double v = fabs(M[r][col]); if (v > best) { best = v; piv = r; } }
                if (piv != col) for (int c = 0; c < 8; ++c) { double t = M[col][c]; M[col][c] = M[piv][c]; M[piv][c] = t; }
                double inv = 1.0 / M[col][col];
                for (int c = 0; c < 8; ++c) M[col][c] *= inv;
                for (int r = 0; r < 4; ++r) if (r != col) {
                    double f = M[r][col];
                    for (int c = 0; c < 8; ++c) M[r][c] -= f * M[col][c];
                }
            }
            for (int r = 0; r < 3; ++r)
                for (int c = 0; c < 4; ++c) {
                    double sm = 0.0;
                    for (int k = 0; k < 4; ++k) sm += M[r][4+k] * (double)posses[k*4 + c];
                    sdiff[r*4 + c] = (float)sm;
                }
        }
        __syncthreads();
        if (j < N) {
            w2[j] = sqrtf(s);
            float c0 = coords[j*3], c1 = coords[j*3+1], c2 = coords[j*3+2];
            float a0 = (sdiff[0]*c0 + sdiff[1]*c1) + (sdiff[2]*c2 + sdiff[3]);
            float a1 = (sdiff[4]*c0 + sdiff[5]*c1) + (sdiff[6]*c2 + sdiff[7]);
            float a2 = (sdiff[8]*c0 + sdiff[9]*c1) + (sdiff[10]*c2 + sdiff[11]);
            alN[j] = make_float4(a0, a1, a2, a0*a0 + a1*a1 + a2*a2);
            int cx = clamp10((int)floorf((a0 + 25.f) * 0.2f));
            int cy = clamp10((int)floorf((a1 + 25.f) * 0.2f));
            int cz = clamp10((int)floorf((a2 + 25.f) * 0.2f));
            int cc = (cz*10 + cy)*10 + cx;
            cellB[j] = cc;
            atomicAdd(&lhist[cc], 1);   // LDS atomic: deterministic count
        }
        __syncthreads();
        for (int c = tid; c < NCELL; c += 256) histB[bx*NCELL + c] = lhist[c];  // [chunk][cell], coalesced
    } else {
        // init: colkey zero (4000 int4) | winnerHi/Lo 0xFF (4000 int4) | flags
        int t0 = (bx-32)*256 + tid;
        int4 z = make_int4(0, 0, 0, 0);
        int4 f = make_int4(-1, -1, -1, -1);
        for (int t = t0; t < 8000; t += 16*256) {
            if (t < 4000) ck4[t] = z;
            else wn4[t-4000] = f;
        }
        if (bx == 32 && tid < 8) flags[tid] = 0;
    }
}

// ---------------- scan: thread-per-cell over [chunk][cell] histogram, in-place -> starts ----------------
__global__ void __launch_bounds__(1024) k_scan(int* __restrict__ h, int* __restrict__ cs) {
    int t = threadIdx.x;
    int v[NCH]; int tot = 0;
    if (t < NCELL) {
        #pragma unroll
        for (int ch = 0; ch < NCH; ++ch) { int x = h[ch*NCELL + t]; v[ch] = x; tot += x; }  // coalesced
    }
    int x = tot;
    int lane = t & 63, wv = t >> 6;
    for (int off = 1; off < 64; off <<= 1) { int y = __shfl_up(x, off); if (lane >= off) x += y; }
    __shared__ int wtot[16];
    if (lane == 63) wtot[wv] = x;
    __syncthreads();
    int wpre = 0;
    for (int k = 0; k < 16; ++k) if (k < wv) wpre += wtot[k];
    int base = wpre + x - tot;   // exclusive prefix over cells
    if (t < NCELL) {
        cs[t] = base;
        int run = base;
        #pragma unroll
        for (int ch = 0; ch < NCH; ++ch) { h[ch*NCELL + t] = run; run += v[ch]; }  // coalesced
    }
    if (t == 0) cs[NCELL] = N;
}

// ---------------- deterministic stable scatter (rank loop int4-vectorized) ----------------
__global__ void k_scatter(const int* __restrict__ cellB, const int* __restrict__ startT,
                          const float* __restrict__ w2, const float4* __restrict__ alN,
                          int* __restrict__ idBR, float* __restrict__ w2R, float4* __restrict__ alR) {
    __shared__ int sc[256];
    int chunk = blockIdx.x, tid = threadIdx.x;
    int gi = chunk*256 + tid;
    int cell = (gi < N) ? cellB[gi] : -1;
    sc[tid] = cell;
    __syncthreads();
    if (gi >= N) return;
    int rank = 0;
    const int4* sc4 = (const int4*)sc;
    int full = tid >> 2;
    for (int t4 = 0; t4 < full; ++t4) {
        int4 q = sc4[t4];
        rank += (q.x == cell) + (q.y == cell) + (q.z == cell) + (q.w == cell);
    }
    for (int t = full*4; t < tid; ++t) rank += (sc[t] == cell);
    int pos = startT[chunk*NCELL + cell] + rank;
    idBR[pos] = gi;
    w2R[pos] = w2[gi];
    alR[pos] = alN[gi];
}

// ---------------- pair pass (round-5 core; ring carries gi/cd/w2 prefetched at filter time) ----------------
__global__ void __launch_bounds__(256) k_pairs(
    const float4* __restrict__ mf4, const float* __restrict__ ori,
    const float4* __restrict__ alR, const float* __restrict__ w2R,
    const float4* __restrict__ sf4, const int* __restrict__ idBR,
    const int* __restrict__ csB,
    unsigned long long* __restrict__ colkey) {
    __shared__ float4 sRow[4][C4];
    __shared__ int bgi[4][128];
    __shared__ float bc[4][128];
    __shared__ float bw[4][128];
    __shared__ int sJ[4][PAIR_CAP];
    __shared__ float sK[4][PAIR_CAP];

    int tid = threadIdx.x, lane = tid & 63, w = tid >> 6;
    int i = blockIdx.x * 4 + w;
    if (lane < C4) sRow[w][lane] = mf4[i*C4 + lane];
    __syncthreads();

    float ox = ori[i*3], oy = ori[i*3+1], oz = ori[i*3+2];
    float xnv = ox*ox + oy*oy + oz*oz;
    float s = 0.f;
    for (int kk = 0; kk < C4; ++kk) {
        float4 v = sRow[w][kk];
        s += v.x*v.x; s += v.y*v.y; s += v.z*v.z; s += v.w*v.w;
    }
    float w1v = sqrtf(s);

    int cx = clamp10((int)floorf((ox + 25.f) * 0.2f));
    int cy = clamp10((int)floorf((oy + 25.f) * 0.2f));
    int cz = clamp10((int)floorf((oz + 25.f) * 0.2f));
    int xlo = max(cx-1, 0), xhi = min(cx+1, 9);

    int s_[9], l_[9], c_[9];
    int tot = 0;
    #pragma unroll
    for (int t = 0; t < 9; ++t) {
        int z = cz + (t/3) - 1, y = cy + (t%3) - 1;
        bool ok = ((unsigned)z <= 9u) && ((unsigned)y <= 9u);
        int ss = 0, ee = 0;
        if (ok) {
            int cbase = (z*10 + y)*10;
            ss = csB[cbase + xlo];
            ee = csB[cbase + xhi + 1];
        }
        s_[t] = ss; l_[t] = ee - ss; c_[t] = tot; tot += ee - ss;
    }

    int cnt = 0, done = 0, npairs = 0;
    float racc = 0.f;
    unsigned long long lmask = (lane == 0) ? 0ull : (~0ull >> (64 - lane));

    auto process = [&](int nb) {
        if (lane < nb) {
            int slot = (done + lane) & 127;
            int gi = bgi[w][slot];
            float cdb = bc[w][slot];
            float w2v = bw[w][slot];
            const float4* br = sf4 + gi*C4;
            float ax = 0.f, ay = 0.f, az = 0.f, aw = 0.f;
            #pragma unroll 4
            for (int kk = 0; kk < C4; ++kk) {
                float4 a = sRow[w][kk];
                float4 b = br[kk];
                ax += a.x*b.x; ay += a.y*b.y; az += a.z*b.z; aw += a.w*b.w;
            }
            float dot = (ax + ay) + (az + aw);
            float fdc = 1.f - dot / fmaxf(w1v * w2v, 1e-8f);
            float dist = (1.f + fdc) - expf(-0.5f * cdb);
            float K = expf(-dist / 0.03f);
            racc += K * U1;
            int sl = npairs + lane;
            if (sl < PAIR_CAP) { sJ[w][sl] = gi; sK[w][sl] = K; }
        }
        npairs += nb;
        done += nb;
    };

    for (int f0 = 0; f0 < tot; f0 += 64) {
        int f = f0 + lane;
        bool act = f < tot;
        int q = 0;
        #pragma unroll
        for (int t = 0; t < 9; ++t) {
            bool in = (f >= c_[t]) && (f - c_[t] < l_[t]);
            if (in) q = s_[t] + (f - c_[t]);
        }
        bool pass = false; float cdv = 0.f;
        int jgi = 0; float jw2 = 0.f;
        if (act) {
            float4 aj = alR[q];
            jgi = idBR[q];            // prefetch off the process critical path
            jw2 = w2R[q];
            float d = xnv + aj.w - 2.f*(ox*aj.x + oy*aj.y + oz*aj.z);
            cdv = fmaxf(d, 0.f) * 4.f;
            pass = cdv < 100.f;
        }
        unsigned long long m = __ballot(pass);
        if (pass) {
            int slot = (cnt + __popcll(m & lmask)) & 127;
            bgi[w][slot] = jgi; bc[w][slot] = cdv; bw[w][slot] = jw2;
        }
        cnt += __popcll(m);
        if (cnt - done >= 64) process(64);
    }
    if (cnt > done) process(cnt - done);

    for (int off = 32; off; off >>= 1) racc += __shfl_xor(racc, off);
    float bi = U1 / (racc + 1e-16f);

    unsigned long long ikey = (unsigned long long)(unsigned)(N - i);
    int np = min(npairs, PAIR_CAP);
    for (int t = lane; t < np; t += 64) {
        float v = sK[w][t] * bi;
        if (v > 0.f) {
            unsigned long long key = ((unsigned long long)__float_as_uint(v) << 32) | ikey;
            atomicMax(&colkey[sJ[w][t]], key);
        }
    }
}

// ---------------- decode colmax -> winner atomics (softmax-on-demand); wave-aggregated flags ----------------
__global__ void k_post(const unsigned long long* __restrict__ colkey,
                       const float* __restrict__ sv_prob, const int* __restrict__ gt,
                       int* __restrict__ winnerHi, int* __restrict__ winnerLo,
                       int* __restrict__ flags) {
    int j = blockIdx.x * 256 + threadIdx.x;
    int lane = threadIdx.x & 63;
    bool valid = j < N;
    float vv = 0.f; int bidx = 0;
    if (valid) {
        unsigned long long key = colkey[j];
        bidx = key ? (N - (int)(key & 0xffffffffull)) : 0;
        const float* p = sv_prob + bidx*OCH;
        float m = -1e30f;
        for (int c = 0; c < OCH; ++c) m = fmaxf(m, p[c]);
        float ssum = 0.f, eg = 0.f; int g = gt[j];
        for (int c = 0; c < OCH; ++c) { float e = expf(p[c] - m); ssum += e; if (c == g) eg = e; }
        vv = eg / ssum;     // identical ops to validated softmax path
    }
    bool hi = valid && (vv > 0.1f);
    bool nothi = valid && !(vv > 0.1f);
    bool lo = valid && (vv > 0.0f);
    bool notlo = valid && !(vv > 0.0f);
    if (hi) atomicMax(&winnerHi[bidx], j);
    if (lo) atomicMax(&winnerLo[bidx], j);
    unsigned long long m0 = __ballot(hi);
    unsigned long long m1 = __ballot(nothi);
    unsigned long long m2 = __ballot(notlo);
    if (lane == 0) {
        if (m0) atomicOr(&flags[0], 1);
        if (m1) atomicOr(&flags[1], 1);
        if (m2) atomicOr(&flags[2], 1);
    }
}

// ---------------- final: blocks 0-7 rowsout, block 8 trust, blocks 9+ passthrough copies ----------------
__global__ void __launch_bounds__(1024) k_final(
    const int* __restrict__ winnerHi, const int* __restrict__ winnerLo,
    const int* __restrict__ flags, const int* __restrict__ gt,
    const float* __restrict__ sv_prob,
    const float* __restrict__ mf, const float* __restrict__ ori,
    float* __restrict__ o_svp, float* __restrict__ o_pre,
    float* __restrict__ out0, float* __restrict__ out5,
    float* __restrict__ o_mf, float* __restrict__ o_ori) {
    int bx = blockIdx.x, tid = threadIdx.x;
    if (bx < 8) {
        const int* winner = flags[0] ? winnerHi : winnerLo;
        int i = bx*1024 + tid;
        if (i >= N) return;
        int w = winner[i];
        if (w >= 0) {
            int g = gt[w];
            for (int c = 0; c < OCH; ++c) o_svp[i*OCH + c] = (c == g) ? 1.f : 0.f;
            o_pre[i] = (float)g;            // argmax of one-hot = g
        } else {
            const float* p = sv_prob + i*OCH;
            float m = -1e30f;
            for (int c = 0; c < OCH; ++c) m = fmaxf(m, p[c]);
            float e[OCH]; float ssum = 0.f;
            for (int c = 0; c < OCH; ++c) { e[c] = expf(p[c] - m); ssum += e[c]; }
            float best = e[0] / ssum; int pidx = 0;
            o_svp[i*OCH] = best;
            for (int c = 1; c < OCH; ++c) {
                float r = e[c] / ssum;
                o_svp[i*OCH + c] = r;
                if (r > best) { best = r; pidx = c; }
            }
            o_pre[i] = (float)pidx;
        }
    } else if (bx == 8) {
        __shared__ int wsum[16];
        const int* winner = flags[0] ? winnerHi : winnerLo;
        int off = flags[0] ? (flags[1] ? 1 : 0) : (flags[2] ? 1 : 0);
        for (int p = tid; p < N; p += 1024) { out0[p] = -1.f; out5[p] = -1.f; }
        __syncthreads();
        int base = 0;
        for (int round = 0; round < N; round += 1024) {
            int i = round + tid;
            int pres = (i < N && winner[i] >= 0) ? 1 : 0;
            unsigned long long mask = __ballot(pres);
            int lane = tid & 63;
            int wv = tid >> 6;
            int excl = (lane == 0) ? 0 : __popcll(mask & (~0ull >> (64 - lane)));
            if (lane == 0) wsum[wv] = __popcll(mask);
            __syncthreads();
            int wpre = 0, tot = 0;
            for (int t = 0; t < 16; ++t) { if (t < wv) wpre += wsum[t]; tot += wsum[t]; }
            int pos = base + wpre + excl + off;
            if (pres && pos < N) { out0[pos] = (float)i; out5[pos] = (float)i; }
            base += tot;
            __syncthreads();
        }
    } else {
        const float4* mf4 = (const float4*)mf;
        const float4* ori4 = (const float4*)ori;
        float4* omf4 = (float4*)o_mf;
        float4* oori4 = (float4*)o_ori;
        int t0 = (bx-9)*1024 + tid;
        for (int t = t0; t < 198000; t += 51*1024) {
            if (t < 192000) omf4[t] = mf4[t];
            else oori4[t-192000] = ori4[t-192000];
        }
    }
}

// ---------------- launch ----------------
extern "C" void kernel_launch(void* const* d_in, const int* in_sizes, int n_in,
                              void* d_out, int out_size, void* d_ws, size_t ws_size,
                              hipStream_t stream) {
    const float* sur_feat   = (const float*)d_in[0];
    const float* sur_coords = (const float*)d_in[1];
    const int*   sur_gt     = (const int*)d_in[2];
    const float* sv_prob    = (const float*)d_in[3];
    const float* mean_feat  = (const float*)d_in[4];
    const float* ori        = (const float*)d_in[5];
    const float* posses     = (const float*)d_in[6];

    float* out = (float*)d_out;
    float* o_trust  = out;
    float* o_mf     = out + 8000;
    float* o_ori    = out + 776000;
    float* o_pre    = out + 800000;
    float* o_svp    = out + 808000;
    float* o_trust2 = out + 960000;

    float* w = (float*)d_ws;
    // 16B-aligned region
    float4* alN = (float4*)w;      w += 4*N;
    float4* alR = (float4*)w;      w += 4*N;
    unsigned long long* colkey = (unsigned long long*)w;  w += 4*N;   // offset 8N floats: 16B-aligned
    // scalar region
    float* w2 = w;                 w += N;
    float* w2R = w;                w += N;
    int* cellB = (int*)w;          w += N;
    int* histB = (int*)w;          w += HSZ;     // [chunk][cell], scanned in-place -> starts
    int* flags = (int*)w;          w += 8;
    int* csB = (int*)w;            w += 1008;
    int* idBR = (int*)w;           w += N;
    int* winnerHi = (int*)w;       w += N;       // contiguous with winnerLo (int4-inited)
    int* winnerLo = (int*)w;       w += N;

    dim3 b256(256);

    k_prep<<<48, b256, 0, stream>>>(sur_feat, sur_coords, posses,
                                    w2, alN, cellB, histB,
                                    (int4*)colkey, (int4*)winnerHi, flags);
    k_scan<<<1, 1024, 0, stream>>>(histB, csB);
    k_scatter<<<32, b256, 0, stream>>>(cellB, histB, w2, alN, idBR, w2R, alR);
    k_pairs<<<N/4, b256, 0, stream>>>((const float4*)mean_feat, ori, alR, w2R,
                                      (const float4*)sur_feat, idBR, csB, colkey);
    k_post<<<32, b256, 0, stream>>>(colkey, sv_prob, sur_gt, winnerHi, winnerLo, flags);
    k_final<<<60, 1024, 0, stream>>>(winnerHi, winnerLo, flags, sur_gt, sv_prob,
                                     mean_feat, ori,
                                     o_svp, o_pre, o_trust, o_trust2, o_mf, o_ori);
}

// Round 9
// 67.841 us; speedup vs baseline: 1.8605x; 1.1055x over previous
//
#include <hip/hip_runtime.h>

#define N 8000
#define C 96
#define C4 24
#define OCH 19
#define NCELL 1000
#define NCH 32
#define HSZ (NCH*NCELL)
#define U1 (1.0f/8000.0f)
#define PAIR_CAP 256

__device__ __forceinline__ int clamp10(int v) { return min(max(v, 0), 9); }

// ---------------- prep: cell/hist (0-31), cooperative w2 norms (32-63), ws init (64-79) ----------------
__global__ void __launch_bounds__(256) k_prep(
    const float* __restrict__ sf, const float* __restrict__ coords,
    const float* __restrict__ posses,
    float* __restrict__ w2, float4* __restrict__ alN,
    int* __restrict__ cellB, int* __restrict__ histB,
    int4* __restrict__ ck4, int4* __restrict__ wn4, int* __restrict__ flags) {
    int bx = blockIdx.x, tid = threadIdx.x;
    if (bx < 32) {
        __shared__ int lhist[NCELL];
        __shared__ float sdiff[12];
        for (int c = tid; c < NCELL; c += 256) lhist[c] = 0;
        int j = bx*256 + tid;
        if (tid == 0) {
            double M[4][8];
            for (int r = 0; r < 4; ++r)
                for (int c = 0; c < 4; ++c) {
                    M[r][c] = (double)posses[16 + r*4 + c];
                    M[r][4+c] = (r == c) ? 1.0 : 0.0;
                }
            for (int col = 0; col < 4; ++col) {
                int piv = col; double best = fabs(M[col][col]);
                for (int r = col+1; r < 4; ++r) { double v = fabs(M[r][col]); if (v > best) { best = v; piv = r; } }
                if (piv != col) for (int c = 0; c < 8; ++c) { double t = M[col][c]; M[col][c] = M[piv][c]; M[piv][c] = t; }
                double inv = 1.0 / M[col][col];
                for (int c = 0; c < 8; ++c) M[col][c] *= inv;
                for (int r = 0; r < 4; ++r) if (r != col) {
                    double f = M[r][col];
                    for (int c = 0; c < 8; ++c) M[r][c] -= f * M[col][c];
                }
            }
            for (int r = 0; r < 3; ++r)
                for (int c = 0; c < 4; ++c) {
                    double sm = 0.0;
                    for (int k = 0; k < 4; ++k) sm += M[r][4+k] * (double)posses[k*4 + c];
                    sdiff[r*4 + c] = (float)sm;
                }
        }
        __syncthreads();
        if (j < N) {
            float c0 = coords[j*3], c1 = coords[j*3+1], c2 = coords[j*3+2];
            float a0 = (sdiff[0]*c0 + sdiff[1]*c1) + (sdiff[2]*c2 + sdiff[3]);
            float a1 = (sdiff[4]*c0 + sdiff[5]*c1) + (sdiff[6]*c2 + sdiff[7]);
            float a2 = (sdiff[8]*c0 + sdiff[9]*c1) + (sdiff[10]*c2 + sdiff[11]);
            alN[j] = make_float4(a0, a1, a2, a0*a0 + a1*a1 + a2*a2);
            int cx = clamp10((int)floorf((a0 + 25.f) * 0.2f));
            int cy = clamp10((int)floorf((a1 + 25.f) * 0.2f));
            int cz = clamp10((int)floorf((a2 + 25.f) * 0.2f));
            int cc = (cz*10 + cy)*10 + cx;
            cellB[j] = cc;
            atomicAdd(&lhist[cc], 1);   // LDS atomic: deterministic count
        }
        __syncthreads();
        for (int c = tid; c < NCELL; c += 256) histB[bx*NCELL + c] = lhist[c];  // [chunk][cell], coalesced
    } else if (bx < 64) {
        // cooperative feature norms: 4 lanes per point, fully-consumed cachelines
        int b = bx - 32;
        int u = tid & 3;
        #pragma unroll
        for (int p0 = 0; p0 < 256; p0 += 64) {
            int jp = b*256 + p0 + (tid >> 2);
            float ax = 0.f, ay = 0.f, az = 0.f, aw = 0.f;
            if (jp < N) {
                const float4* s4 = (const float4*)sf + jp*C4;
                #pragma unroll
                for (int s2 = 0; s2 < 6; ++s2) {
                    float4 v = s4[s2*4 + u];
                    ax += v.x*v.x; ay += v.y*v.y; az += v.z*v.z; aw += v.w*v.w;
                }
            }
            float pp = (ax + ay) + (az + aw);
            pp += __shfl_xor(pp, 1);
            pp += __shfl_xor(pp, 2);
            if (jp < N && u == 0) w2[jp] = sqrtf(pp);
        }
    } else {
        // init: colkey zero (4000 int4) | winnerHi/Lo 0xFF (4000 int4) | flags
        int t0 = (bx-64)*256 + tid;
        int4 z = make_int4(0, 0, 0, 0);
        int4 f = make_int4(-1, -1, -1, -1);
        for (int t = t0; t < 8000; t += 16*256) {
            if (t < 4000) ck4[t] = z;
            else wn4[t-4000] = f;
        }
        if (bx == 64 && tid < 8) flags[tid] = 0;
    }
}

// ---------------- scan: thread-per-cell over [chunk][cell] histogram, in-place -> starts ----------------
__global__ void __launch_bounds__(1024) k_scan(int* __restrict__ h, int* __restrict__ cs) {
    int t = threadIdx.x;
    int v[NCH]; int tot = 0;
    if (t < NCELL) {
        #pragma unroll
        for (int ch = 0; ch < NCH; ++ch) { int x = h[ch*NCELL + t]; v[ch] = x; tot += x; }  // coalesced
    }
    int x = tot;
    int lane = t & 63, wv = t >> 6;
    for (int off = 1; off < 64; off <<= 1) { int y = __shfl_up(x, off); if (lane >= off) x += y; }
    __shared__ int wtot[16];
    if (lane == 63) wtot[wv] = x;
    __syncthreads();
    int wpre = 0;
    for (int k = 0; k < 16; ++k) if (k < wv) wpre += wtot[k];
    int base = wpre + x - tot;   // exclusive prefix over cells
    if (t < NCELL) {
        cs[t] = base;
        int run = base;
        #pragma unroll
        for (int ch = 0; ch < NCH; ++ch) { h[ch*NCELL + t] = run; run += v[ch]; }  // coalesced
    }
    if (t == 0) cs[NCELL] = N;
}

// ---------------- deterministic stable scatter (rank loop int4-vectorized) ----------------
__global__ void k_scatter(const int* __restrict__ cellB, const int* __restrict__ startT,
                          const float* __restrict__ w2, const float4* __restrict__ alN,
                          int* __restrict__ idBR, float* __restrict__ w2R, float4* __restrict__ alR) {
    __shared__ int sc[256];
    int chunk = blockIdx.x, tid = threadIdx.x;
    int gi = chunk*256 + tid;
    int cell = (gi < N) ? cellB[gi] : -1;
    sc[tid] = cell;
    __syncthreads();
    if (gi >= N) return;
    int rank = 0;
    const int4* sc4 = (const int4*)sc;
    int full = tid >> 2;
    for (int t4 = 0; t4 < full; ++t4) {
        int4 q = sc4[t4];
        rank += (q.x == cell) + (q.y == cell) + (q.z == cell) + (q.w == cell);
    }
    for (int t = full*4; t < tid; ++t) rank += (sc[t] == cell);
    int pos = startT[chunk*NCELL + cell] + rank;
    idBR[pos] = gi;
    w2R[pos] = w2[gi];
    alR[pos] = alN[gi];
}

// ---------------- pair pass: filter -> compact -> 4-lane cooperative dot -> K -> b -> colmax ----------------
__global__ void __launch_bounds__(256) k_pairs(
    const float4* __restrict__ mf4, const float* __restrict__ ori,
    const float4* __restrict__ alR, const float* __restrict__ w2R,
    const float4* __restrict__ sf4, const int* __restrict__ idBR,
    const int* __restrict__ csB,
    unsigned long long* __restrict__ colkey) {
    __shared__ float4 sRow[4][C4];
    __shared__ int bgi[4][128];
    __shared__ float bc[4][128];
    __shared__ float bw[4][128];
    __shared__ int sJ[4][PAIR_CAP];
    __shared__ float sK[4][PAIR_CAP];

    int tid = threadIdx.x, lane = tid & 63, w = tid >> 6;
    int i = blockIdx.x * 4 + w;
    if (lane < C4) sRow[w][lane] = mf4[i*C4 + lane];
    __syncthreads();

    float ox = ori[i*3], oy = ori[i*3+1], oz = ori[i*3+2];
    float xnv = ox*ox + oy*oy + oz*oz;
    float s = 0.f;
    for (int kk = 0; kk < C4; ++kk) {
        float4 v = sRow[w][kk];
        s += v.x*v.x; s += v.y*v.y; s += v.z*v.z; s += v.w*v.w;
    }
    float w1v = sqrtf(s);

    int cx = clamp10((int)floorf((ox + 25.f) * 0.2f));
    int cy = clamp10((int)floorf((oy + 25.f) * 0.2f));
    int cz = clamp10((int)floorf((oz + 25.f) * 0.2f));
    int xlo = max(cx-1, 0), xhi = min(cx+1, 9);

    int s_[9], l_[9], c_[9];
    int tot = 0;
    #pragma unroll
    for (int t = 0; t < 9; ++t) {
        int z = cz + (t/3) - 1, y = cy + (t%3) - 1;
        bool ok = ((unsigned)z <= 9u) && ((unsigned)y <= 9u);
        int ss = 0, ee = 0;
        if (ok) {
            int cbase = (z*10 + y)*10;
            ss = csB[cbase + xlo];
            ee = csB[cbase + xhi + 1];
        }
        s_[t] = ss; l_[t] = ee - ss; c_[t] = tot; tot += ee - ss;
    }

    int cnt = 0, done = 0, npairs = 0;
    float racc = 0.f;
    unsigned long long lmask = (lane == 0) ? 0ull : (~0ull >> (64 - lane));
    int gu = lane & 3, gt_ = lane >> 2;

    // 16 pairs per call; 4 lanes cooperate per pair: lane u loads float4 kk=s2*4+u,
    // so each (s2, group) covers exactly one 64B line — 6 fully-consumed lines/pair-group.
    auto process16 = [&](int nb) {
        int slot = (done + gt_) & 127;
        int gi = bgi[w][slot];          // 4-lane broadcast reads
        float cdb = bc[w][slot];
        float w2v = bw[w][slot];
        float dotp = 0.f;
        if (gt_ < nb) {
            const float4* br = sf4 + gi*C4;
            float ax = 0.f, ay = 0.f, az = 0.f, aw = 0.f;
            #pragma unroll
            for (int s2 = 0; s2 < 6; ++s2) {
                int kk = s2*4 + gu;
                float4 a = sRow[w][kk];
                float4 b = br[kk];
                ax += a.x*b.x; ay += a.y*b.y; az += a.z*b.z; aw += a.w*b.w;
            }
            dotp = (ax + ay) + (az + aw);
        }
        dotp += __shfl_xor(dotp, 1);
        dotp += __shfl_xor(dotp, 2);
        if (gt_ < nb && gu == 0) {
            float fdc = 1.f - dotp / fmaxf(w1v * w2v, 1e-8f);
            float dist = (1.f + fdc) - expf(-0.5f * cdb);
            float K = expf(-dist / 0.03f);
            racc += K * U1;
            int sl = npairs + gt_;
            if (sl < PAIR_CAP) { sJ[w][sl] = gi; sK[w][sl] = K; }
        }
        npairs += nb;
        done += nb;
    };

    for (int f0 = 0; f0 < tot; f0 += 64) {
        int f = f0 + lane;
        bool act = f < tot;
        int q = 0;
        #pragma unroll
        for (int t = 0; t < 9; ++t) {
            bool in = (f >= c_[t]) && (f - c_[t] < l_[t]);
            if (in) q = s_[t] + (f - c_[t]);
        }
        bool pass = false; float cdv = 0.f;
        int jgi = 0; float jw2 = 0.f;
        if (act) {
            float4 aj = alR[q];
            jgi = idBR[q];
            jw2 = w2R[q];
            float d = xnv + aj.w - 2.f*(ox*aj.x + oy*aj.y + oz*aj.z);
            cdv = fmaxf(d, 0.f) * 4.f;
            pass = cdv < 100.f;
        }
        unsigned long long m = __ballot(pass);
        if (pass) {
            int slot = (cnt + __popcll(m & lmask)) & 127;
            bgi[w][slot] = jgi; bc[w][slot] = cdv; bw[w][slot] = jw2;
        }
        cnt += __popcll(m);
        if (cnt - done >= 64) {
            process16(16); process16(16); process16(16); process16(16);
        }
    }
    while (cnt > done) {
        int nb = cnt - done; if (nb > 16) nb = 16;
        process16(nb);
    }

    for (int off = 32; off; off >>= 1) racc += __shfl_xor(racc, off);
    float bi = U1 / (racc + 1e-16f);

    unsigned long long ikey = (unsigned long long)(unsigned)(N - i);
    int np = min(npairs, PAIR_CAP);
    for (int t = lane; t < np; t += 64) {
        float v = sK[w][t] * bi;
        if (v > 0.f) {
            unsigned long long key = ((unsigned long long)__float_as_uint(v) << 32) | ikey;
            atomicMax(&colkey[sJ[w][t]], key);
        }
    }
}

// ---------------- decode colmax -> winner atomics (softmax-on-demand); wave-aggregated flags ----------------
__global__ void k_post(const unsigned long long* __restrict__ colkey,
                       const float* __restrict__ sv_prob, const int* __restrict__ gt,
                       int* __restrict__ winnerHi, int* __restrict__ winnerLo,
                       int* __restrict__ flags) {
    int j = blockIdx.x * 256 + threadIdx.x;
    int lane = threadIdx.x & 63;
    bool valid = j < N;
    float vv = 0.f; int bidx = 0;
    if (valid) {
        unsigned long long key = colkey[j];
        bidx = key ? (N - (int)(key & 0xffffffffull)) : 0;
        const float* p = sv_prob + bidx*OCH;
        float m = -1e30f;
        for (int c = 0; c < OCH; ++c) m = fmaxf(m, p[c]);
        float ssum = 0.f, eg = 0.f; int g = gt[j];
        for (int c = 0; c < OCH; ++c) { float e = expf(p[c] - m); ssum += e; if (c == g) eg = e; }
        vv = eg / ssum;
    }
    bool hi = valid && (vv > 0.1f);
    bool nothi = valid && !(vv > 0.1f);
    bool lo = valid && (vv > 0.0f);
    bool notlo = valid && !(vv > 0.0f);
    if (hi) atomicMax(&winnerHi[bidx], j);
    if (lo) atomicMax(&winnerLo[bidx], j);
    unsigned long long m0 = __ballot(hi);
    unsigned long long m1 = __ballot(nothi);
    unsigned long long m2 = __ballot(notlo);
    if (lane == 0) {
        if (m0) atomicOr(&flags[0], 1);
        if (m1) atomicOr(&flags[1], 1);
        if (m2) atomicOr(&flags[2], 1);
    }
}

// ---------------- final: blocks 0-7 rowsout, block 8 trust, blocks 9+ passthrough copies ----------------
__global__ void __launch_bounds__(1024) k_final(
    const int* __restrict__ winnerHi, const int* __restrict__ winnerLo,
    const int* __restrict__ flags, const int* __restrict__ gt,
    const float* __restrict__ sv_prob,
    const float* __restrict__ mf, const float* __restrict__ ori,
    float* __restrict__ o_svp, float* __restrict__ o_pre,
    float* __restrict__ out0, float* __restrict__ out5,
    float* __restrict__ o_mf, float* __restrict__ o_ori) {
    int bx = blockIdx.x, tid = threadIdx.x;
    if (bx < 8) {
        const int* winner = flags[0] ? winnerHi : winnerLo;
        int i = bx*1024 + tid;
        if (i >= N) return;
        int w = winner[i];
        if (w >= 0) {
            int g = gt[w];
            for (int c = 0; c < OCH; ++c) o_svp[i*OCH + c] = (c == g) ? 1.f : 0.f;
            o_pre[i] = (float)g;
        } else {
            const float* p = sv_prob + i*OCH;
            float m = -1e30f;
            for (int c = 0; c < OCH; ++c) m = fmaxf(m, p[c]);
            float e[OCH]; float ssum = 0.f;
            for (int c = 0; c < OCH; ++c) { e[c] = expf(p[c] - m); ssum += e[c]; }
            float best = e[0] / ssum; int pidx = 0;
            o_svp[i*OCH] = best;
            for (int c = 1; c < OCH; ++c) {
                float r = e[c] / ssum;
                o_svp[i*OCH + c] = r;
                if (r > best) { best = r; pidx = c; }
            }
            o_pre[i] = (float)pidx;
        }
    } else if (bx == 8) {
        __shared__ int wsum[16];
        const int* winner = flags[0] ? winnerHi : winnerLo;
        int off = flags[0] ? (flags[1] ? 1 : 0) : (flags[2] ? 1 : 0);
        for (int p = tid; p < N; p += 1024) { out0[p] = -1.f; out5[p] = -1.f; }
        __syncthreads();
        int base = 0;
        for (int round = 0; round < N; round += 1024) {
            int i = round + tid;
            int pres = (i < N && winner[i] >= 0) ? 1 : 0;
            unsigned long long mask = __ballot(pres);
            int lane = tid & 63;
            int wv = tid >> 6;
            int excl = (lane == 0) ? 0 : __popcll(mask & (~0ull >> (64 - lane)));
            if (lane == 0) wsum[wv] = __popcll(mask);
            __syncthreads();
            int wpre = 0, tot = 0;
            for (int t = 0; t < 16; ++t) { if (t < wv) wpre += wsum[t]; tot += wsum[t]; }
            int pos = base + wpre + excl + off;
            if (pres && pos < N) { out0[pos] = (float)i; out5[pos] = (float)i; }
            base += tot;
            __syncthreads();
        }
    } else {
        const float4* mf4 = (const float4*)mf;
        const float4* ori4 = (const float4*)ori;
        float4* omf4 = (float4*)o_mf;
        float4* oori4 = (float4*)o_ori;
        int t0 = (bx-9)*1024 + tid;
        for (int t = t0; t < 198000; t += 51*1024) {
            if (t < 192000) omf4[t] = mf4[t];
            else oori4[t-192000] = ori4[t-192000];
        }
    }
}

// ---------------- launch ----------------
extern "C" void kernel_launch(void* const* d_in, const int* in_sizes, int n_in,
                              void* d_out, int out_size, void* d_ws, size_t ws_size,
                              hipStream_t stream) {
    const float* sur_feat   = (const float*)d_in[0];
    const float* sur_coords = (const float*)d_in[1];
    const int*   sur_gt     = (const int*)d_in[2];
    const float* sv_prob    = (const float*)d_in[3];
    const float* mean_feat  = (const float*)d_in[4];
    const float* ori        = (const float*)d_in[5];
    const float* posses     = (const float*)d_in[6];

    float* out = (float*)d_out;
    float* o_trust  = out;
    float* o_mf     = out + 8000;
    float* o_ori    = out + 776000;
    float* o_pre    = out + 800000;
    float* o_svp    = out + 808000;
    float* o_trust2 = out + 960000;

    float* w = (float*)d_ws;
    // 16B-aligned region
    float4* alN = (float4*)w;      w += 4*N;
    float4* alR = (float4*)w;      w += 4*N;
    unsigned long long* colkey = (unsigned long long*)w;  w += 4*N;
    // scalar region
    float* w2 = w;                 w += N;
    float* w2R = w;                w += N;
    int* cellB = (int*)w;          w += N;
    int* histB = (int*)w;          w += HSZ;     // [chunk][cell], scanned in-place -> starts
    int* flags = (int*)w;          w += 8;
    int* csB = (int*)w;            w += 1008;
    int* idBR = (int*)w;           w += N;
    int* winnerHi = (int*)w;       w += N;
    int* winnerLo = (int*)w;       w += N;

    dim3 b256(256);

    k_prep<<<80, b256, 0, stream>>>(sur_feat, sur_coords, posses,
                                    w2, alN, cellB, histB,
                                    (int4*)colkey, (int4*)winnerHi, flags);
    k_scan<<<1, 1024, 0, stream>>>(histB, csB);
    k_scatter<<<32, b256, 0, stream>>>(cellB, histB, w2, alN, idBR, w2R, alR);
    k_pairs<<<N/4, b256, 0, stream>>>((const float4*)mean_feat, ori, alR, w2R,
                                      (const float4*)sur_feat, idBR, csB, colkey);
    k_post<<<32, b256, 0, stream>>>(colkey, sv_prob, sur_gt, winnerHi, winnerLo, flags);
    k_final<<<60, 1024, 0, stream>>>(winnerHi, winnerLo, flags, sur_gt, sv_prob,
                                     mean_feat, ori,
                                     o_svp, o_pre, o_trust, o_trust2, o_mf, o_ori);
}

// Round 10
// 66.703 us; speedup vs baseline: 1.8922x; 1.0171x over previous
//
#include <hip/hip_runtime.h>

#define N 8000
#define C 96
#define C4 24
#define OCH 19
#define NCELL 1000
#define NCH 32
#define HSZ (NCH*NCELL)
#define U1 (1.0f/8000.0f)
#define PAIR_CAP 256

__device__ __forceinline__ int clamp10(int v) { return min(max(v, 0), 9); }

// ---------------- prep: cell/hist (0-31), cooperative w2 norms (32-63), ws init (64-79) ----------------
__global__ void __launch_bounds__(256) k_prep(
    const float* __restrict__ sf, const float* __restrict__ coords,
    const float* __restrict__ posses,
    float* __restrict__ w2, float4* __restrict__ alN,
    int* __restrict__ cellB, int* __restrict__ histB,
    int4* __restrict__ ck4, int4* __restrict__ wn4, int* __restrict__ flags) {
    int bx = blockIdx.x, tid = threadIdx.x;
    if (bx < 32) {
        __shared__ int lhist[NCELL];
        __shared__ float sdiff[12];
        for (int c = tid; c < NCELL; c += 256) lhist[c] = 0;
        int j = bx*256 + tid;
        if (tid == 0) {
            double M[4][8];
            for (int r = 0; r < 4; ++r)
                for (int c = 0; c < 4; ++c) {
                    M[r][c] = (double)posses[16 + r*4 + c];
                    M[r][4+c] = (r == c) ? 1.0 : 0.0;
                }
            for (int col = 0; col < 4; ++col) {
                int piv = col; double best = fabs(M[col][col]);
                for (int r = col+1; r < 4; ++r) { double v = fabs(M[r][col]); if (v > best) { best = v; piv = r; } }
                if (piv != col) for (int c = 0; c < 8; ++c) { double t = M[col][c]; M[col][c] = M[piv][c]; M[piv][c] = t; }
                double inv = 1.0 / M[col][col];
                for (int c = 0; c < 8; ++c) M[col][c] *= inv;
                for (int r = 0; r < 4; ++r) if (r != col) {
                    double f = M[r][col];
                    for (int c = 0; c < 8; ++c) M[r][c] -= f * M[col][c];
                }
            }
            for (int r = 0; r < 3; ++r)
                for (int c = 0; c < 4; ++c) {
                    double sm = 0.0;
                    for (int k = 0; k < 4; ++k) sm += M[r][4+k] * (double)posses[k*4 + c];
                    sdiff[r*4 + c] = (float)sm;
                }
        }
        __syncthreads();
        if (j < N) {
            float c0 = coords[j*3], c1 = coords[j*3+1], c2 = coords[j*3+2];
            float a0 = (sdiff[0]*c0 + sdiff[1]*c1) + (sdiff[2]*c2 + sdiff[3]);
            float a1 = (sdiff[4]*c0 + sdiff[5]*c1) + (sdiff[6]*c2 + sdiff[7]);
            float a2 = (sdiff[8]*c0 + sdiff[9]*c1) + (sdiff[10]*c2 + sdiff[11]);
            alN[j] = make_float4(a0, a1, a2, a0*a0 + a1*a1 + a2*a2);
            int cx = clamp10((int)floorf((a0 + 25.f) * 0.2f));
            int cy = clamp10((int)floorf((a1 + 25.f) * 0.2f));
            int cz = clamp10((int)floorf((a2 + 25.f) * 0.2f));
            int cc = (cz*10 + cy)*10 + cx;
            cellB[j] = cc;
            atomicAdd(&lhist[cc], 1);   // LDS atomic: deterministic count
        }
        __syncthreads();
        for (int c = tid; c < NCELL; c += 256) histB[bx*NCELL + c] = lhist[c];  // [chunk][cell], coalesced
    } else if (bx < 64) {
        // cooperative feature norms: 4 lanes per point, fully-consumed cachelines
        int b = bx - 32;
        int u = tid & 3;
        #pragma unroll
        for (int p0 = 0; p0 < 256; p0 += 64) {
            int jp = b*256 + p0 + (tid >> 2);
            float ax = 0.f, ay = 0.f, az = 0.f, aw = 0.f;
            if (jp < N) {
                const float4* s4 = (const float4*)sf + jp*C4;
                #pragma unroll
                for (int s2 = 0; s2 < 6; ++s2) {
                    float4 v = s4[s2*4 + u];
                    ax += v.x*v.x; ay += v.y*v.y; az += v.z*v.z; aw += v.w*v.w;
                }
            }
            float pp = (ax + ay) + (az + aw);
            pp += __shfl_xor(pp, 1);
            pp += __shfl_xor(pp, 2);
            if (jp < N && u == 0) w2[jp] = sqrtf(pp);
        }
    } else {
        // init: colkey zero (4000 int4) | winnerHi/Lo 0xFF (4000 int4) | flags
        int t0 = (bx-64)*256 + tid;
        int4 z = make_int4(0, 0, 0, 0);
        int4 f = make_int4(-1, -1, -1, -1);
        for (int t = t0; t < 8000; t += 16*256) {
            if (t < 4000) ck4[t] = z;
            else wn4[t-4000] = f;
        }
        if (bx == 64 && tid < 8) flags[tid] = 0;
    }
}

// ---------------- scatter with in-block histogram scan (replaces k_scan node) ----------------
__global__ void __launch_bounds__(256) k_scatter(
    const int* __restrict__ cellB, const int* __restrict__ h,
    const float* __restrict__ w2, const float4* __restrict__ alN,
    int* __restrict__ idBR, float* __restrict__ w2R, float4* __restrict__ alR,
    int* __restrict__ csB) {
    __shared__ int sStart[NCELL];
    __shared__ int wtot[4];
    __shared__ int sc[256];
    int chunk = blockIdx.x, tid = threadIdx.x;

    // per-thread 4 consecutive cells: total over chunks + prefix over chunks < this chunk
    int tot0 = 0, tot1 = 0, tot2 = 0, tot3 = 0;
    int pre0 = 0, pre1 = 0, pre2 = 0, pre3 = 0;
    bool cv = tid < 250;
    if (cv) {
        for (int ch = 0; ch < NCH; ++ch) {
            int4 v = ((const int4*)(h + ch*NCELL))[tid];   // coalesced int4
            tot0 += v.x; tot1 += v.y; tot2 += v.z; tot3 += v.w;
            if (ch < chunk) { pre0 += v.x; pre1 += v.y; pre2 += v.z; pre3 += v.w; }
        }
    }
    int S = tot0 + tot1 + tot2 + tot3;
    int lane = tid & 63, wv = tid >> 6;
    int x = S;
    for (int off = 1; off < 64; off <<= 1) { int y = __shfl_up(x, off); if (lane >= off) x += y; }
    if (lane == 63) wtot[wv] = x;
    __syncthreads();
    int wpre = 0;
    for (int k = 0; k < 4; ++k) if (k < wv) wpre += wtot[k];
    int run = wpre + x - S;   // exclusive prefix over this thread's cells
    if (cv) {
        int c = tid*4;
        sStart[c]   = run + pre0; if (chunk == 0) csB[c]   = run; run += tot0;
        sStart[c+1] = run + pre1; if (chunk == 0) csB[c+1] = run; run += tot1;
        sStart[c+2] = run + pre2; if (chunk == 0) csB[c+2] = run; run += tot2;
        sStart[c+3] = run + pre3; if (chunk == 0) csB[c+3] = run; run += tot3;
    }
    if (chunk == 0 && tid == 0) csB[NCELL] = N;

    // stable scatter (rank loop int4-vectorized)
    int gi = chunk*256 + tid;
    int cell = (gi < N) ? cellB[gi] : -1;
    sc[tid] = cell;
    __syncthreads();
    if (gi >= N) return;
    int rank = 0;
    const int4* sc4 = (const int4*)sc;
    int full = tid >> 2;
    for (int t4 = 0; t4 < full; ++t4) {
        int4 q = sc4[t4];
        rank += (q.x == cell) + (q.y == cell) + (q.z == cell) + (q.w == cell);
    }
    for (int t = full*4; t < tid; ++t) rank += (sc[t] == cell);
    int pos = sStart[cell] + rank;
    idBR[pos] = gi;
    w2R[pos] = w2[gi];
    alR[pos] = alN[gi];
}

// ---------------- pair pass: pipelined filter -> compact -> 4-lane cooperative dot -> K -> b -> colmax ----------------
__global__ void __launch_bounds__(256) k_pairs(
    const float4* __restrict__ mf4, const float* __restrict__ ori,
    const float4* __restrict__ alR, const float* __restrict__ w2R,
    const float4* __restrict__ sf4, const int* __restrict__ idBR,
    const int* __restrict__ csB,
    unsigned long long* __restrict__ colkey) {
    __shared__ float4 sRow[4][C4];
    __shared__ int bgi[4][128];
    __shared__ float bc[4][128];
    __shared__ float bw[4][128];
    __shared__ int sJ[4][PAIR_CAP];
    __shared__ float sK[4][PAIR_CAP];

    int tid = threadIdx.x, lane = tid & 63, w = tid >> 6;
    int i = blockIdx.x * 4 + w;
    if (lane < C4) sRow[w][lane] = mf4[i*C4 + lane];
    __syncthreads();

    float ox = ori[i*3], oy = ori[i*3+1], oz = ori[i*3+2];
    float xnv = ox*ox + oy*oy + oz*oz;
    float s = 0.f;
    for (int kk = 0; kk < C4; ++kk) {
        float4 v = sRow[w][kk];
        s += v.x*v.x; s += v.y*v.y; s += v.z*v.z; s += v.w*v.w;
    }
    float w1v = sqrtf(s);

    int cx = clamp10((int)floorf((ox + 25.f) * 0.2f));
    int cy = clamp10((int)floorf((oy + 25.f) * 0.2f));
    int cz = clamp10((int)floorf((oz + 25.f) * 0.2f));
    int xlo = max(cx-1, 0), xhi = min(cx+1, 9);

    int s_[9], l_[9], c_[9];
    int tot = 0;
    #pragma unroll
    for (int t = 0; t < 9; ++t) {
        int z = cz + (t/3) - 1, y = cy + (t%3) - 1;
        bool ok = ((unsigned)z <= 9u) && ((unsigned)y <= 9u);
        int ss = 0, ee = 0;
        if (ok) {
            int cbase = (z*10 + y)*10;
            ss = csB[cbase + xlo];
            ee = csB[cbase + xhi + 1];
        }
        s_[t] = ss; l_[t] = ee - ss; c_[t] = tot; tot += ee - ss;
    }

    auto calcq = [&](int f) -> int {
        int q = 0;
        #pragma unroll
        for (int t = 0; t < 9; ++t) {
            bool in = (f >= c_[t]) && (f - c_[t] < l_[t]);
            if (in) q = s_[t] + (f - c_[t]);
        }
        return q;
    };

    int cnt = 0, done = 0, npairs = 0;
    float racc = 0.f;
    unsigned long long lmask = (lane == 0) ? 0ull : (~0ull >> (64 - lane));
    int gu = lane & 3, gt_ = lane >> 2;

    // 16 pairs per call; 4 lanes cooperate per pair (lane u covers float4 kk=s2*4+u,
    // one fully-consumed 64B line per (s2, group)).
    auto process16 = [&](int nb) {
        int slot = (done + gt_) & 127;
        int gi = bgi[w][slot];          // 4-lane broadcast reads
        float cdb = bc[w][slot];
        float w2v = bw[w][slot];
        float dotp = 0.f;
        if (gt_ < nb) {
            const float4* br = sf4 + gi*C4;
            float ax = 0.f, ay = 0.f, az = 0.f, aw = 0.f;
            #pragma unroll
            for (int s2 = 0; s2 < 6; ++s2) {
                int kk = s2*4 + gu;
                float4 a = sRow[w][kk];
                float4 b = br[kk];
                ax += a.x*b.x; ay += a.y*b.y; az += a.z*b.z; aw += a.w*b.w;
            }
            dotp = (ax + ay) + (az + aw);
        }
        dotp += __shfl_xor(dotp, 1);
        dotp += __shfl_xor(dotp, 2);
        if (gt_ < nb && gu == 0) {
            float fdc = 1.f - dotp / fmaxf(w1v * w2v, 1e-8f);
            float dist = (1.f + fdc) - expf(-0.5f * cdb);
            float K = expf(-dist / 0.03f);
            racc += K * U1;
            int sl = npairs + gt_;
            if (sl < PAIR_CAP) { sJ[w][sl] = gi; sK[w][sl] = K; }
        }
        npairs += nb;
        done += nb;
    };

    // software-pipelined filter: iteration t+1's candidate loads issue before
    // iteration t's ballot/compact/process (loads depend only on f0, not ring state)
    bool act_cur = lane < tot;
    float4 aj_cur = make_float4(0.f, 0.f, 0.f, 0.f);
    int gi_cur = 0; float w2_cur = 0.f;
    if (act_cur) {
        int q = calcq(lane);
        aj_cur = alR[q]; gi_cur = idBR[q]; w2_cur = w2R[q];
    }
    for (int f0 = 0; f0 < tot; f0 += 64) {
        int fn = f0 + 64 + lane;
        bool act_n = fn < tot;
        float4 aj_n = make_float4(0.f, 0.f, 0.f, 0.f);
        int gi_n = 0; float w2_n = 0.f;
        if (act_n) {
            int qn = calcq(fn);
            aj_n = alR[qn]; gi_n = idBR[qn]; w2_n = w2R[qn];
        }
        bool pass = false; float cdv = 0.f;
        if (act_cur) {
            float d = xnv + aj_cur.w - 2.f*(ox*aj_cur.x + oy*aj_cur.y + oz*aj_cur.z);
            cdv = fmaxf(d, 0.f) * 4.f;
            pass = cdv < 100.f;
        }
        unsigned long long m = __ballot(pass);
        if (pass) {
            int slot = (cnt + __popcll(m & lmask)) & 127;
            bgi[w][slot] = gi_cur; bc[w][slot] = cdv; bw[w][slot] = w2_cur;
        }
        cnt += __popcll(m);
        if (cnt - done >= 64) {
            process16(16); process16(16); process16(16); process16(16);
        }
        aj_cur = aj_n; gi_cur = gi_n; w2_cur = w2_n; act_cur = act_n;
    }
    while (cnt > done) {
        int nb = cnt - done; if (nb > 16) nb = 16;
        process16(nb);
    }

    for (int off = 32; off; off >>= 1) racc += __shfl_xor(racc, off);
    float bi = U1 / (racc + 1e-16f);

    unsigned long long ikey = (unsigned long long)(unsigned)(N - i);
    int np = min(npairs, PAIR_CAP);
    for (int t = lane; t < np; t += 64) {
        float v = sK[w][t] * bi;
        if (v > 0.f) {
            unsigned long long key = ((unsigned long long)__float_as_uint(v) << 32) | ikey;
            atomicMax(&colkey[sJ[w][t]], key);
        }
    }
}

// ---------------- decode colmax -> winner atomics (softmax-on-demand); wave-aggregated flags ----------------
__global__ void k_post(const unsigned long long* __restrict__ colkey,
                       const float* __restrict__ sv_prob, const int* __restrict__ gt,
                       int* __restrict__ winnerHi, int* __restrict__ winnerLo,
                       int* __restrict__ flags) {
    int j = blockIdx.x * 256 + threadIdx.x;
    int lane = threadIdx.x & 63;
    bool valid = j < N;
    float vv = 0.f; int bidx = 0;
    if (valid) {
        unsigned long long key = colkey[j];
        bidx = key ? (N - (int)(key & 0xffffffffull)) : 0;
        const float* p = sv_prob + bidx*OCH;
        float m = -1e30f;
        for (int c = 0; c < OCH; ++c) m = fmaxf(m, p[c]);
        float ssum = 0.f, eg = 0.f; int g = gt[j];
        for (int c = 0; c < OCH; ++c) { float e = expf(p[c] - m); ssum += e; if (c == g) eg = e; }
        vv = eg / ssum;
    }
    bool hi = valid && (vv > 0.1f);
    bool nothi = valid && !(vv > 0.1f);
    bool lo = valid && (vv > 0.0f);
    bool notlo = valid && !(vv > 0.0f);
    if (hi) atomicMax(&winnerHi[bidx], j);
    if (lo) atomicMax(&winnerLo[bidx], j);
    unsigned long long m0 = __ballot(hi);
    unsigned long long m1 = __ballot(nothi);
    unsigned long long m2 = __ballot(notlo);
    if (lane == 0) {
        if (m0) atomicOr(&flags[0], 1);
        if (m1) atomicOr(&flags[1], 1);
        if (m2) atomicOr(&flags[2], 1);
    }
}

// ---------------- final: blocks 0-7 rowsout, block 8 trust, blocks 9+ passthrough copies ----------------
__global__ void __launch_bounds__(1024) k_final(
    const int* __restrict__ winnerHi, const int* __restrict__ winnerLo,
    const int* __restrict__ flags, const int* __restrict__ gt,
    const float* __restrict__ sv_prob,
    const float* __restrict__ mf, const float* __restrict__ ori,
    float* __restrict__ o_svp, float* __restrict__ o_pre,
    float* __restrict__ out0, float* __restrict__ out5,
    float* __restrict__ o_mf, float* __restrict__ o_ori) {
    int bx = blockIdx.x, tid = threadIdx.x;
    if (bx < 8) {
        const int* winner = flags[0] ? winnerHi : winnerLo;
        int i = bx*1024 + tid;
        if (i >= N) return;
        int w = winner[i];
        if (w >= 0) {
            int g = gt[w];
            for (int c = 0; c < OCH; ++c) o_svp[i*OCH + c] = (c == g) ? 1.f : 0.f;
            o_pre[i] = (float)g;
        } else {
            const float* p = sv_prob + i*OCH;
            float m = -1e30f;
            for (int c = 0; c < OCH; ++c) m = fmaxf(m, p[c]);
            float e[OCH]; float ssum = 0.f;
            for (int c = 0; c < OCH; ++c) { e[c] = expf(p[c] - m); ssum += e[c]; }
            float best = e[0] / ssum; int pidx = 0;
            o_svp[i*OCH] = best;
            for (int c = 1; c < OCH; ++c) {
                float r = e[c] / ssum;
                o_svp[i*OCH + c] = r;
                if (r > best) { best = r; pidx = c; }
            }
            o_pre[i] = (float)pidx;
        }
    } else if (bx == 8) {
        __shared__ int wsum[16];
        const int* winner = flags[0] ? winnerHi : winnerLo;
        int off = flags[0] ? (flags[1] ? 1 : 0) : (flags[2] ? 1 : 0);
        for (int p = tid; p < N; p += 1024) { out0[p] = -1.f; out5[p] = -1.f; }
        __syncthreads();
        int base = 0;
        for (int round = 0; round < N; round += 1024) {
            int i = round + tid;
            int pres = (i < N && winner[i] >= 0) ? 1 : 0;
            unsigned long long mask = __ballot(pres);
            int lane = tid & 63;
            int wv = tid >> 6;
            int excl = (lane == 0) ? 0 : __popcll(mask & (~0ull >> (64 - lane)));
            if (lane == 0) wsum[wv] = __popcll(mask);
            __syncthreads();
            int wpre = 0, tot = 0;
            for (int t = 0; t < 16; ++t) { if (t < wv) wpre += wsum[t]; tot += wsum[t]; }
            int pos = base + wpre + excl + off;
            if (pres && pos < N) { out0[pos] = (float)i; out5[pos] = (float)i; }
            base += tot;
            __syncthreads();
        }
    } else {
        const float4* mf4 = (const float4*)mf;
        const float4* ori4 = (const float4*)ori;
        float4* omf4 = (float4*)o_mf;
        float4* oori4 = (float4*)o_ori;
        int t0 = (bx-9)*1024 + tid;
        for (int t = t0; t < 198000; t += 51*1024) {
            if (t < 192000) omf4[t] = mf4[t];
            else oori4[t-192000] = ori4[t-192000];
        }
    }
}

// ---------------- launch ----------------
extern "C" void kernel_launch(void* const* d_in, const int* in_sizes, int n_in,
                              void* d_out, int out_size, void* d_ws, size_t ws_size,
                              hipStream_t stream) {
    const float* sur_feat   = (const float*)d_in[0];
    const float* sur_coords = (const float*)d_in[1];
    const int*   sur_gt     = (const int*)d_in[2];
    const float* sv_prob    = (const float*)d_in[3];
    const float* mean_feat  = (const float*)d_in[4];
    const float* ori        = (const float*)d_in[5];
    const float* posses     = (const float*)d_in[6];

    float* out = (float*)d_out;
    float* o_trust  = out;
    float* o_mf     = out + 8000;
    float* o_ori    = out + 776000;
    float* o_pre    = out + 800000;
    float* o_svp    = out + 808000;
    float* o_trust2 = out + 960000;

    float* w = (float*)d_ws;
    // 16B-aligned region
    float4* alN = (float4*)w;      w += 4*N;
    float4* alR = (float4*)w;      w += 4*N;
    unsigned long long* colkey = (unsigned long long*)w;  w += 4*N;
    // scalar region
    float* w2 = w;                 w += N;
    float* w2R = w;                w += N;
    int* cellB = (int*)w;          w += N;
    int* histB = (int*)w;          w += HSZ;     // [chunk][cell]
    int* flags = (int*)w;          w += 8;
    int* csB = (int*)w;            w += 1008;
    int* idBR = (int*)w;           w += N;
    int* winnerHi = (int*)w;       w += N;
    int* winnerLo = (int*)w;       w += N;

    dim3 b256(256);

    k_prep<<<80, b256, 0, stream>>>(sur_feat, sur_coords, posses,
                                    w2, alN, cellB, histB,
                                    (int4*)colkey, (int4*)winnerHi, flags);
    k_scatter<<<32, b256, 0, stream>>>(cellB, histB, w2, alN, idBR, w2R, alR, csB);
    k_pairs<<<N/4, b256, 0, stream>>>((const float4*)mean_feat, ori, alR, w2R,
                                      (const float4*)sur_feat, idBR, csB, colkey);
    k_post<<<32, b256, 0, stream>>>(colkey, sv_prob, sur_gt, winnerHi, winnerLo, flags);
    k_final<<<60, 1024, 0, stream>>>(winnerHi, winnerLo, flags, sur_gt, sv_prob,
                                     mean_feat, ori,
                                     o_svp, o_pre, o_trust, o_trust2, o_mf, o_ori);
}